// Round 1
// 2359.731 us; speedup vs baseline: 1.1052x; 1.1052x over previous
//
#include <hip/hip_runtime.h>

#define DH  20         // hidden width
#define BSH 6          // log2 nodes per CSR-build bucket
#define BSZ 64         // nodes per bucket

// ---------------- setup kernels ----------------

__global__ void init_deg(int* __restrict__ out_deg, int* __restrict__ in_deg, int n) {
    int i = blockIdx.x * blockDim.x + threadIdx.x;
    if (i < n) { out_deg[i] = 1; in_deg[i] = 1; }   // self-loop contributes 1 to each
}

__global__ void count_deg(const int* __restrict__ src, const int* __restrict__ dst,
                          int* __restrict__ out_deg, int* __restrict__ in_deg, int E) {
    int e = blockIdx.x * blockDim.x + threadIdx.x;
    if (e < E) {
        atomicAdd(&out_deg[src[e]], 1);
        atomicAdd(&in_deg[dst[e]], 1);
    }
}

__global__ void compute_norm(const int* __restrict__ out_deg, const int* __restrict__ in_deg,
                             double* __restrict__ dout, double* __restrict__ din, int n) {
    int i = blockIdx.x * blockDim.x + threadIdx.x;
    if (i < n) {
        dout[i] = 1.0 / sqrt((double)out_deg[i]);
        din[i]  = 1.0 / sqrt((double)in_deg[i]);
    }
}

// Single-block exclusive scan of (in_deg[i]-1) -> row_ptr
__global__ void build_rowptr(const int* __restrict__ in_deg, int* __restrict__ row_ptr,
                             int n_nodes, int n_edges) {
    __shared__ int lds[1024];
    int t = threadIdx.x;
    int chunk = (n_nodes + 1023) / 1024;
    int lo = t * chunk;
    int hi = lo + chunk; if (hi > n_nodes) hi = n_nodes;
    int s = 0;
    for (int i = lo; i < hi; ++i) s += in_deg[i] - 1;
    lds[t] = s;
    __syncthreads();
    for (int off = 1; off < 1024; off <<= 1) {
        int v = (t >= off) ? lds[t - off] : 0;
        __syncthreads();
        lds[t] += v;
        __syncthreads();
    }
    int run = lds[t] - s;   // exclusive prefix of this chunk
    for (int i = lo; i < hi; ++i) {
        row_ptr[i] = run;
        run += in_deg[i] - 1;
    }
    if (t == 0) row_ptr[n_nodes] = n_edges;
}

// ---------------- bucketed CSR build (replaces scattered fill_csr) ----------------
// Old fill_csr: random 4B col stores -> 194MB HBM writes (16x amplification), 286us.
// New: pass1 appends into per-bucket streams (line-combinable), pass2 scatters
// inside an 8KB L2-hot window per block with LDS cursors -> full-line writebacks.

__global__ void init_bcursor(const int* __restrict__ row_ptr, int* __restrict__ cursor_b,
                             int nb) {
    int bkt = blockIdx.x * blockDim.x + threadIdx.x;
    if (bkt < nb) cursor_b[bkt] = row_ptr[bkt << BSH];
}

__global__ void bucket_scatter(const int* __restrict__ src, const int* __restrict__ dst,
                               int* __restrict__ cursor_b, int* __restrict__ pairs, int E) {
    int e = blockIdx.x * blockDim.x + threadIdx.x;
    if (e < E) {
        int d = dst[e];
        int slot = atomicAdd(&cursor_b[d >> BSH], 1);
        // src < 2^17, so (src<<6 | dst&63) fits easily in 31 bits
        pairs[slot] = (src[e] << BSH) | (d & (BSZ - 1));
    }
}

__global__ __launch_bounds__(256) void bucket_fill(const int* __restrict__ row_ptr,
        const int* __restrict__ pairs, int* __restrict__ col, int n_nodes) {
    __shared__ int lc[BSZ];
    int base = blockIdx.x << BSH;
    int nrem = n_nodes - base; if (nrem > BSZ) nrem = BSZ;
    if ((int)threadIdx.x < nrem) lc[threadIdx.x] = row_ptr[base + threadIdx.x];
    __syncthreads();
    int start = row_ptr[base];
    int end   = row_ptr[base + nrem];
    for (int e = start + (int)threadIdx.x; e < end; e += 256) {
        int pk = __builtin_nontemporal_load(&pairs[e]);
        int slot = atomicAdd(&lc[pk & (BSZ - 1)], 1);   // LDS atomic, cheap
        col[slot] = pk >> BSH;                          // write inside 8KB window
    }
}

// ---------------- layer kernels ----------------

// x0[n] = feat[n] * dout[n]   (layer 0 input is N x 1)
__global__ void compute_x0(const float* __restrict__ feat, const double* __restrict__ dout,
                           double* __restrict__ x0, int n) {
    int i = blockIdx.x * blockDim.x + threadIdx.x;
    if (i < n) x0[i] = (double)feat[i] * dout[i];
}

// layer 0: g[n] = x0[n] + sum_{s in N(n)} x0[s]  (scalar gather, 64 lanes edge-parallel)
__global__ __launch_bounds__(256) void layer_start(
        const double* __restrict__ x0, const int* __restrict__ row_ptr,
        const int* __restrict__ col, const double* __restrict__ din,
        const double* __restrict__ dout, const float* __restrict__ W,
        const float* __restrict__ b, float* __restrict__ xout, int n_nodes) {
    int n    = (blockIdx.x * blockDim.x + threadIdx.x) >> 6;   // one wave per node
    int lane = threadIdx.x & 63;
    if (n >= n_nodes) return;
    double a = (lane == 0) ? x0[n] : 0.0;   // self loop
    int e0 = row_ptr[n], e1 = row_ptr[n + 1];
    for (int e = e0 + lane; e < e1; e += 64)
        a += x0[__builtin_nontemporal_load(&col[e])];
#pragma unroll
    for (int off = 32; off > 0; off >>= 1)
        a += __shfl_xor(a, off, 64);
    if (lane < DH) {
        double v = a * din[n] * (double)W[lane] + (double)b[lane];
        float r = fmaxf((float)v, 0.0f);
        xout[(long)n * DH + lane] = (float)((double)r * dout[n]);
    }
}

// dense transform: y[n] = h'[n] @ W   (h' already carries the dout scaling).
// Matches reference order (hw = (h*dout)@W before segment_sum). Coalesced,
// W broadcast from LDS, double accumulation. Tiny (~5us/layer).
__global__ __launch_bounds__(256) void transform(
        const float* __restrict__ h, const float* __restrict__ W,
        float* __restrict__ y, int n_nodes) {
    __shared__ float Wl[DH * DH];
    for (int i = threadIdx.x; i < DH * DH; i += blockDim.x) Wl[i] = W[i];
    __syncthreads();
    int n = blockIdx.x * blockDim.x + threadIdx.x;
    if (n >= n_nodes) return;
    const float4* h4 = (const float4*)(h + (size_t)n * DH);
    float4 a0 = h4[0], a1 = h4[1], a2 = h4[2], a3 = h4[3], a4 = h4[4];
    float hv[DH] = {a0.x, a0.y, a0.z, a0.w, a1.x, a1.y, a1.z, a1.w,
                    a2.x, a2.y, a2.z, a2.w, a3.x, a3.y, a3.z, a3.w,
                    a4.x, a4.y, a4.z, a4.w};
    double acc[DH];
#pragma unroll
    for (int j = 0; j < DH; ++j) acc[j] = 0.0;
#pragma unroll
    for (int k = 0; k < DH; ++k) {
        double hk = (double)hv[k];
#pragma unroll
        for (int j = 0; j < DH; ++j)
            acc[j] += hk * (double)Wl[k * DH + j];   // LDS broadcast, conflict-free
    }
    float4* y4 = (float4*)(y + (size_t)n * DH);
    y4[0] = make_float4((float)acc[0],  (float)acc[1],  (float)acc[2],  (float)acc[3]);
    y4[1] = make_float4((float)acc[4],  (float)acc[5],  (float)acc[6],  (float)acc[7]);
    y4[2] = make_float4((float)acc[8],  (float)acc[9],  (float)acc[10], (float)acc[11]);
    y4[3] = make_float4((float)acc[12], (float)acc[13], (float)acc[14], (float)acc[15]);
    y4[4] = make_float4((float)acc[16], (float)acc[17], (float)acc[18], (float)acc[19]);
}

// gather+aggregate: h'[n] = relu(din[n]*(y[n] + sum_{s in N(n)} y[s]) + b) * dout[n]
// One wave per node. lane = 5*ep + jq; ep in [0,12) edge slot, jq float4 quarter.
// Per-lane direct col loads (no shfl distribute) -> shorter dependency chain.
// No matvec tail (moved to transform) -> wave ends right after the folds.
__global__ __launch_bounds__(256, 8) void gather_agg(
        const float* __restrict__ y, const int* __restrict__ row_ptr,
        const int* __restrict__ col, const double* __restrict__ din,
        const double* __restrict__ dout, const float* __restrict__ b,
        float* __restrict__ hout, int n_nodes, int mode) {
    int n    = (blockIdx.x * blockDim.x + threadIdx.x) >> 6;   // one wave per node
    int lane = threadIdx.x & 63;
    if (n >= n_nodes) return;

    int ep = lane / 5;           // edge slot 0..12 (lanes 60..63 -> ep=12, inactive)
    int jq = lane - ep * 5;      // float4 quarter 0..4
    const float4* __restrict__ y4 = (const float4*)y;

    int e0 = row_ptr[n], e1 = row_ptr[n + 1];

    // direct per-lane index loads: col[e0..e0+48) spans <=4 lines; the 5 lanes of
    // each ep share an address -> coalesced. Independent of any cross-lane op.
    int s0 = -1, s1 = -1, s2 = -1, s3 = -1;
    if (ep < 12) {
        int p = e0 + ep;
        if (p      < e1) s0 = __builtin_nontemporal_load(&col[p]);
        if (p + 12 < e1) s1 = __builtin_nontemporal_load(&col[p + 12]);
        if (p + 24 < e1) s2 = __builtin_nontemporal_load(&col[p + 24]);
        if (p + 36 < e1) s3 = __builtin_nontemporal_load(&col[p + 36]);
    }
    bool p0 = s0 >= 0, p1 = s1 >= 0, p2 = s2 >= 0, p3 = s3 >= 0;
    // unconditional gathers (invalid slots read the L1-hot self row, masked out)
    float4 v0 = y4[(p0 ? s0 : n) * 5 + jq];
    float4 v1 = y4[(p1 ? s1 : n) * 5 + jq];
    float4 v2 = y4[(p2 ? s2 : n) * 5 + jq];
    float4 v3 = y4[(p3 ? s3 : n) * 5 + jq];

    double g[4] = {0.0, 0.0, 0.0, 0.0};
    if (ep == 0) {               // self loop handled by slot 0
        float4 v = y4[n * 5 + jq];
        g[0] = (double)v.x; g[1] = (double)v.y; g[2] = (double)v.z; g[3] = (double)v.w;
    }
    if (p0) { g[0] += (double)v0.x; g[1] += (double)v0.y; g[2] += (double)v0.z; g[3] += (double)v0.w; }
    if (p1) { g[0] += (double)v1.x; g[1] += (double)v1.y; g[2] += (double)v1.z; g[3] += (double)v1.w; }
    if (p2) { g[0] += (double)v2.x; g[1] += (double)v2.y; g[2] += (double)v2.z; g[3] += (double)v2.w; }
    if (p3) { g[0] += (double)v3.x; g[1] += (double)v3.y; g[2] += (double)v3.z; g[3] += (double)v3.w; }

    // rare tail: deg > 48 (wave-uniform branch)
    if (e1 - e0 > 48) {
        if (ep < 12) {
            for (int e = e0 + 48 + ep; e < e1; e += 12) {
                int s = __builtin_nontemporal_load(&col[e]);
                float4 v = y4[s * 5 + jq];
                g[0] += (double)v.x; g[1] += (double)v.y;
                g[2] += (double)v.z; g[3] += (double)v.w;
            }
        }
    }

    // fold 12 edge slots down to slot 0 (lanes 0..4 hold g[0..3] = features 4*jq..4*jq+3)
#define FOLD(LIM, DELTA)                                                        \
    {                                                                           \
        int srcl = lane + DELTA; if (srcl > 63) srcl = lane;                    \
        double t0 = __shfl(g[0], srcl, 64);                                     \
        double t1 = __shfl(g[1], srcl, 64);                                     \
        double t2 = __shfl(g[2], srcl, 64);                                     \
        double t3 = __shfl(g[3], srcl, 64);                                     \
        if (ep < (LIM)) { g[0] += t0; g[1] += t1; g[2] += t2; g[3] += t3; }     \
    }
    FOLD(4, 40)   // ep(0..3)  += ep+8
    FOLD(4, 20)   // ep(0..3)  += ep+4
    FOLD(2, 10)   // ep(0..1)  += ep+2
    FOLD(1, 5)    // ep(0)     += ep+1
#undef FOLD

    if (lane < 5) {
        double dn = din[n];
        float4 bb = ((const float4*)b)[lane];    // b row is 16B-aligned (80B stride)
        double o0 = g[0] * dn + (double)bb.x;
        double o1 = g[1] * dn + (double)bb.y;
        double o2 = g[2] * dn + (double)bb.z;
        double o3 = g[3] * dn + (double)bb.w;
        float4 w;
        if (mode == 0) {
            double dd = dout[n];
            w.x = (float)((double)fmaxf((float)o0, 0.0f) * dd);
            w.y = (float)((double)fmaxf((float)o1, 0.0f) * dd);
            w.z = (float)((double)fmaxf((float)o2, 0.0f) * dd);
            w.w = (float)((double)fmaxf((float)o3, 0.0f) * dd);
        } else {
            w.x = (float)o0; w.y = (float)o1; w.z = (float)o2; w.w = (float)o3;
        }
        ((float4*)(hout + (size_t)n * DH))[lane] = w;   // 5 lanes x 16B = 80B row
    }
}

// ---------------- launch ----------------

static inline size_t align256(size_t x) { return (x + 255) & ~(size_t)255; }

extern "C" void kernel_launch(void* const* d_in, const int* in_sizes, int n_in,
                              void* d_out, int out_size, void* d_ws, size_t ws_size,
                              hipStream_t stream) {
    const float* feat    = (const float*)d_in[0];
    const float* W_start = (const float*)d_in[1];
    const float* b_start = (const float*)d_in[2];
    const float* W_mid   = (const float*)d_in[3];
    const float* b_mid   = (const float*)d_in[4];
    const float* W_final = (const float*)d_in[5];
    const float* b_final = (const float*)d_in[6];
    const int*   src     = (const int*)d_in[7];
    const int*   dst     = (const int*)d_in[8];

    const int N = in_sizes[0];              // 100000
    const int E = in_sizes[7];              // 3200000
    const int L = in_sizes[3] / (DH * DH);  // 18 mid layers
    const int NB = (N + BSZ - 1) / BSZ;     // CSR-build buckets

    // workspace carve-up
    char* p = (char*)d_ws;
    double* dout_d = (double*)p; p += align256(sizeof(double) * N);
    double* din_d  = (double*)p; p += align256(sizeof(double) * N);
    double* x0     = (double*)p; p += align256(sizeof(double) * N);
    int* out_deg   = (int*)p;    p += align256(sizeof(int) * N);
    int* in_deg    = (int*)p;    p += align256(sizeof(int) * N);
    int* row_ptr   = (int*)p;    p += align256(sizeof(int) * (N + 1));
    int* cursor_b  = (int*)p;    p += align256(sizeof(int) * NB);
    int* col       = (int*)p;    p += align256(sizeof(int) * E);
    float* hbuf    = (float*)p;  p += align256(sizeof(float) * N * DH);
    float* ybuf    = (float*)p;  p += align256(sizeof(float) * N * DH);
    // pairs (E ints = 12.8MB) overlays hbuf+ybuf (16MB); dead before layer_start
    int* pairs = (int*)hbuf;

    const int BT = 256;
    int grid_n  = (N + BT - 1) / BT;
    int grid_e  = (E + BT - 1) / BT;
    int grid_nw = (N + 3) / 4;              // 1 wave per node, 4 waves per block

    // ---- graph setup ----
    init_deg<<<grid_n, BT, 0, stream>>>(out_deg, in_deg, N);
    count_deg<<<grid_e, BT, 0, stream>>>(src, dst, out_deg, in_deg, E);
    compute_norm<<<grid_n, BT, 0, stream>>>(out_deg, in_deg, dout_d, din_d, N);
    build_rowptr<<<1, 1024, 0, stream>>>(in_deg, row_ptr, N, E);
    init_bcursor<<<(NB + BT - 1) / BT, BT, 0, stream>>>(row_ptr, cursor_b, NB);
    bucket_scatter<<<grid_e, BT, 0, stream>>>(src, dst, cursor_b, pairs, E);
    bucket_fill<<<NB, BT, 0, stream>>>(row_ptr, pairs, col, N);

    // ---- layer 0 (scalar input) ----
    compute_x0<<<grid_n, BT, 0, stream>>>(feat, dout_d, x0, N);
    layer_start<<<grid_nw, BT, 0, stream>>>(x0, row_ptr, col, din_d, dout_d,
                                            W_start, b_start, hbuf, N);

    // ---- 18 mid layers: dense transform + gather-aggregate ----
    for (int l = 0; l < L; ++l) {
        transform<<<grid_n, BT, 0, stream>>>(hbuf, W_mid + (size_t)l * DH * DH, ybuf, N);
        gather_agg<<<grid_nw, BT, 0, stream>>>(ybuf, row_ptr, col, din_d, dout_d,
                                               b_mid + (size_t)l * DH, hbuf, N, 0);
    }

    // ---- final layer: raw store to d_out ----
    transform<<<grid_n, BT, 0, stream>>>(hbuf, W_final, ybuf, N);
    gather_agg<<<grid_nw, BT, 0, stream>>>(ybuf, row_ptr, col, din_d, dout_d,
                                           b_final, (float*)d_out, N, 1);
}

// Round 2
// 1949.839 us; speedup vs baseline: 1.3375x; 1.2102x over previous
//
#include <hip/hip_runtime.h>

#define DH   20        // hidden width
#define BKS  10        // log2 nodes per coarse bucket
#define BKN  1024      // nodes per coarse bucket
#define MAXK 128       // max buckets (N=100000 -> K=98)
#define CHUNK 16384    // edges per bucket_place block

// ---------------- setup kernels ----------------

__global__ void init_outdeg(int* __restrict__ out_deg, int n) {
    int i = blockIdx.x * blockDim.x + threadIdx.x;
    if (i < n) out_deg[i] = 1;              // self-loop contributes 1
}

__global__ void zero_bhist(int* __restrict__ bhist, int K) {
    int i = threadIdx.x;
    if (i <= K) bhist[i] = 0;
}

__global__ void count_outdeg(const int* __restrict__ src, int* __restrict__ out_deg, int E) {
    int e = blockIdx.x * blockDim.x + threadIdx.x;
    if (e < E) atomicAdd(&out_deg[src[e]], 1);
}

// global per-bucket histogram, LDS-aggregated (196*98 global atomics, not 3.2M)
__global__ __launch_bounds__(256) void bucket_hist(const int* __restrict__ dst,
        int* __restrict__ bhist, int E, int K) {
    __shared__ int h[MAXK];
    for (int i = threadIdx.x; i < K; i += blockDim.x) h[i] = 0;
    __syncthreads();
    int lo = blockIdx.x * CHUNK;
    int hi = lo + CHUNK; if (hi > E) hi = E;
    for (int e = lo + (int)threadIdx.x; e < hi; e += 256)
        atomicAdd(&h[__builtin_nontemporal_load(&dst[e]) >> BKS], 1);
    __syncthreads();
    for (int i = threadIdx.x; i < K; i += blockDim.x)
        if (h[i]) atomicAdd(&bhist[i], h[i]);
}

// exclusive scan of bucket histogram -> contiguous bucket regions + cursors
__global__ void bucket_scan(const int* __restrict__ bhist, int* __restrict__ bbase,
                            int* __restrict__ bcursor, int K) {
    if (threadIdx.x == 0) {
        int run = 0;
        for (int k = 0; k < K; ++k) {
            bbase[k] = run; bcursor[k] = run;
            run += bhist[k];
        }
        bbase[K] = run;
    }
}

// block counting-sort: LDS histogram of a 16K-edge chunk -> one global atomicAdd
// per (block,bucket) reserves a ~670B contiguous run -> near-full-line writes.
__global__ __launch_bounds__(256) void bucket_place(const int* __restrict__ src,
        const int* __restrict__ dst, int* __restrict__ bcursor,
        int* __restrict__ pairs, int E, int K) {
    __shared__ int h[MAXK];
    __shared__ int rbase[MAXK];
    int lo = blockIdx.x * CHUNK;
    int hi = lo + CHUNK; if (hi > E) hi = E;
    for (int i = threadIdx.x; i < K; i += blockDim.x) h[i] = 0;
    __syncthreads();
    for (int e = lo + (int)threadIdx.x; e < hi; e += 256)
        atomicAdd(&h[__builtin_nontemporal_load(&dst[e]) >> BKS], 1);
    __syncthreads();
    for (int i = threadIdx.x; i < K; i += blockDim.x) {
        rbase[i] = h[i] ? atomicAdd(&bcursor[i], h[i]) : 0;
        h[i] = 0;
    }
    __syncthreads();
    for (int e = lo + (int)threadIdx.x; e < hi; e += 256) {
        int d = __builtin_nontemporal_load(&dst[e]);
        int bk = d >> BKS;
        int pos = atomicAdd(&h[bk], 1);
        // src < 2^17, so (src<<10 | dst&1023) fits in 27 bits
        pairs[rbase[bk] + pos] = (__builtin_nontemporal_load(&src[e]) << BKS) | (d & (BKN - 1));
    }
}

// per-node in-degree from bucket-contiguous pairs: LDS histogram, zero global atomics
__global__ __launch_bounds__(256) void node_indeg(const int* __restrict__ bbase,
        const int* __restrict__ pairs, int* __restrict__ in_deg, int n_nodes) {
    __shared__ int h[BKN];
    int k = blockIdx.x;
    int nbase = k << BKS;
    int nrem = n_nodes - nbase; if (nrem > BKN) nrem = BKN;
    for (int i = threadIdx.x; i < nrem; i += 256) h[i] = 1;   // self loop
    __syncthreads();
    int e0 = bbase[k], e1 = bbase[k + 1];
    for (int e = e0 + (int)threadIdx.x; e < e1; e += 256)
        atomicAdd(&h[__builtin_nontemporal_load(&pairs[e]) & (BKN - 1)], 1);
    __syncthreads();
    for (int i = threadIdx.x; i < nrem; i += 256) in_deg[nbase + i] = h[i];
}

__global__ void compute_norm(const int* __restrict__ out_deg, const int* __restrict__ in_deg,
                             double* __restrict__ dout, double* __restrict__ din, int n) {
    int i = blockIdx.x * blockDim.x + threadIdx.x;
    if (i < n) {
        dout[i] = 1.0 / sqrt((double)out_deg[i]);
        din[i]  = 1.0 / sqrt((double)in_deg[i]);
    }
}

// Single-block exclusive scan of (in_deg[i]-1) -> row_ptr
__global__ void build_rowptr(const int* __restrict__ in_deg, int* __restrict__ row_ptr,
                             int n_nodes, int n_edges) {
    __shared__ int lds[1024];
    int t = threadIdx.x;
    int chunk = (n_nodes + 1023) / 1024;
    int lo = t * chunk;
    int hi = lo + chunk; if (hi > n_nodes) hi = n_nodes;
    int s = 0;
    for (int i = lo; i < hi; ++i) s += in_deg[i] - 1;
    lds[t] = s;
    __syncthreads();
    for (int off = 1; off < 1024; off <<= 1) {
        int v = (t >= off) ? lds[t - off] : 0;
        __syncthreads();
        lds[t] += v;
        __syncthreads();
    }
    int run = lds[t] - s;   // exclusive prefix of this chunk
    for (int i = lo; i < hi; ++i) {
        row_ptr[i] = run;
        run += in_deg[i] - 1;
    }
    if (t == 0) row_ptr[n_nodes] = n_edges;
}

// scatter bucket stream into CSR: LDS cursors, col writes confined to a ~131KB
// L2-hot window per block -> full-line writebacks.
__global__ __launch_bounds__(256) void bucket_fill(const int* __restrict__ row_ptr,
        const int* __restrict__ bbase, const int* __restrict__ pairs,
        int* __restrict__ col, int n_nodes) {
    __shared__ int lc[BKN];
    int k = blockIdx.x;
    int nbase = k << BKS;
    int nrem = n_nodes - nbase; if (nrem > BKN) nrem = BKN;
    for (int i = threadIdx.x; i < nrem; i += 256) lc[i] = row_ptr[nbase + i];
    __syncthreads();
    int e0 = bbase[k], e1 = bbase[k + 1];
    for (int e = e0 + (int)threadIdx.x; e < e1; e += 256) {
        int pk = __builtin_nontemporal_load(&pairs[e]);
        int slot = atomicAdd(&lc[pk & (BKN - 1)], 1);   // LDS atomic, cheap
        col[slot] = pk >> BKS;
    }
}

// ---------------- layer kernels ----------------

// x0[n] = feat[n] * dout[n]   (layer 0 input is N x 1)
__global__ void compute_x0(const float* __restrict__ feat, const double* __restrict__ dout,
                           double* __restrict__ x0, int n) {
    int i = blockIdx.x * blockDim.x + threadIdx.x;
    if (i < n) x0[i] = (double)feat[i] * dout[i];
}

// layer 0: g[n] = x0[n] + sum_{s in N(n)} x0[s]  (scalar gather, 64 lanes edge-parallel)
__global__ __launch_bounds__(256) void layer_start(
        const double* __restrict__ x0, const int* __restrict__ row_ptr,
        const int* __restrict__ col, const double* __restrict__ din,
        const double* __restrict__ dout, const float* __restrict__ W,
        const float* __restrict__ b, float* __restrict__ xout, int n_nodes) {
    int n    = (blockIdx.x * blockDim.x + threadIdx.x) >> 6;   // one wave per node
    int lane = threadIdx.x & 63;
    if (n >= n_nodes) return;
    double a = (lane == 0) ? x0[n] : 0.0;   // self loop
    int e0 = row_ptr[n], e1 = row_ptr[n + 1];
    for (int e = e0 + lane; e < e1; e += 64)
        a += x0[__builtin_nontemporal_load(&col[e])];
#pragma unroll
    for (int off = 32; off > 0; off >>= 1)
        a += __shfl_xor(a, off, 64);
    if (lane < DH) {
        double v = a * din[n] * (double)W[lane] + (double)b[lane];
        float r = fmaxf((float)v, 0.0f);
        xout[(long)n * DH + lane] = (float)((double)r * dout[n]);
    }
}

// dense transform: y[n] = h'[n] @ W   (h' already carries the dout scaling).
__global__ __launch_bounds__(256) void transform(
        const float* __restrict__ h, const float* __restrict__ W,
        float* __restrict__ y, int n_nodes) {
    __shared__ float Wl[DH * DH];
    for (int i = threadIdx.x; i < DH * DH; i += blockDim.x) Wl[i] = W[i];
    __syncthreads();
    int n = blockIdx.x * blockDim.x + threadIdx.x;
    if (n >= n_nodes) return;
    const float4* h4 = (const float4*)(h + (size_t)n * DH);
    float4 a0 = h4[0], a1 = h4[1], a2 = h4[2], a3 = h4[3], a4 = h4[4];
    float hv[DH] = {a0.x, a0.y, a0.z, a0.w, a1.x, a1.y, a1.z, a1.w,
                    a2.x, a2.y, a2.z, a2.w, a3.x, a3.y, a3.z, a3.w,
                    a4.x, a4.y, a4.z, a4.w};
    double acc[DH];
#pragma unroll
    for (int j = 0; j < DH; ++j) acc[j] = 0.0;
#pragma unroll
    for (int k = 0; k < DH; ++k) {
        double hk = (double)hv[k];
#pragma unroll
        for (int j = 0; j < DH; ++j)
            acc[j] += hk * (double)Wl[k * DH + j];   // LDS broadcast, conflict-free
    }
    float4* y4 = (float4*)(y + (size_t)n * DH);
    y4[0] = make_float4((float)acc[0],  (float)acc[1],  (float)acc[2],  (float)acc[3]);
    y4[1] = make_float4((float)acc[4],  (float)acc[5],  (float)acc[6],  (float)acc[7]);
    y4[2] = make_float4((float)acc[8],  (float)acc[9],  (float)acc[10], (float)acc[11]);
    y4[3] = make_float4((float)acc[12], (float)acc[13], (float)acc[14], (float)acc[15]);
    y4[4] = make_float4((float)acc[16], (float)acc[17], (float)acc[18], (float)acc[19]);
}

// gather+aggregate: h'[n] = relu(din[n]*(y[n] + sum_{s in N(n)} y[s]) + b) * dout[n]
__global__ __launch_bounds__(256, 8) void gather_agg(
        const float* __restrict__ y, const int* __restrict__ row_ptr,
        const int* __restrict__ col, const double* __restrict__ din,
        const double* __restrict__ dout, const float* __restrict__ b,
        float* __restrict__ hout, int n_nodes, int mode) {
    int n    = (blockIdx.x * blockDim.x + threadIdx.x) >> 6;   // one wave per node
    int lane = threadIdx.x & 63;
    if (n >= n_nodes) return;

    int ep = lane / 5;           // edge slot 0..12 (lanes 60..63 -> ep=12, inactive)
    int jq = lane - ep * 5;      // float4 quarter 0..4
    const float4* __restrict__ y4 = (const float4*)y;

    int e0 = row_ptr[n], e1 = row_ptr[n + 1];

    int s0 = -1, s1 = -1, s2 = -1, s3 = -1;
    if (ep < 12) {
        int p = e0 + ep;
        if (p      < e1) s0 = __builtin_nontemporal_load(&col[p]);
        if (p + 12 < e1) s1 = __builtin_nontemporal_load(&col[p + 12]);
        if (p + 24 < e1) s2 = __builtin_nontemporal_load(&col[p + 24]);
        if (p + 36 < e1) s3 = __builtin_nontemporal_load(&col[p + 36]);
    }
    bool p0 = s0 >= 0, p1 = s1 >= 0, p2 = s2 >= 0, p3 = s3 >= 0;
    float4 v0 = y4[(p0 ? s0 : n) * 5 + jq];
    float4 v1 = y4[(p1 ? s1 : n) * 5 + jq];
    float4 v2 = y4[(p2 ? s2 : n) * 5 + jq];
    float4 v3 = y4[(p3 ? s3 : n) * 5 + jq];

    double g[4] = {0.0, 0.0, 0.0, 0.0};
    if (ep == 0) {               // self loop handled by slot 0
        float4 v = y4[n * 5 + jq];
        g[0] = (double)v.x; g[1] = (double)v.y; g[2] = (double)v.z; g[3] = (double)v.w;
    }
    if (p0) { g[0] += (double)v0.x; g[1] += (double)v0.y; g[2] += (double)v0.z; g[3] += (double)v0.w; }
    if (p1) { g[0] += (double)v1.x; g[1] += (double)v1.y; g[2] += (double)v1.z; g[3] += (double)v1.w; }
    if (p2) { g[0] += (double)v2.x; g[1] += (double)v2.y; g[2] += (double)v2.z; g[3] += (double)v2.w; }
    if (p3) { g[0] += (double)v3.x; g[1] += (double)v3.y; g[2] += (double)v3.z; g[3] += (double)v3.w; }

    // rare tail: deg > 48 (wave-uniform branch)
    if (e1 - e0 > 48) {
        if (ep < 12) {
            for (int e = e0 + 48 + ep; e < e1; e += 12) {
                int s = __builtin_nontemporal_load(&col[e]);
                float4 v = y4[s * 5 + jq];
                g[0] += (double)v.x; g[1] += (double)v.y;
                g[2] += (double)v.z; g[3] += (double)v.w;
            }
        }
    }

    // fold 12 edge slots down to slot 0
#define FOLD(LIM, DELTA)                                                        \
    {                                                                           \
        int srcl = lane + DELTA; if (srcl > 63) srcl = lane;                    \
        double t0 = __shfl(g[0], srcl, 64);                                     \
        double t1 = __shfl(g[1], srcl, 64);                                     \
        double t2 = __shfl(g[2], srcl, 64);                                     \
        double t3 = __shfl(g[3], srcl, 64);                                     \
        if (ep < (LIM)) { g[0] += t0; g[1] += t1; g[2] += t2; g[3] += t3; }     \
    }
    FOLD(4, 40)   // ep(0..3)  += ep+8
    FOLD(4, 20)   // ep(0..3)  += ep+4
    FOLD(2, 10)   // ep(0..1)  += ep+2
    FOLD(1, 5)    // ep(0)     += ep+1
#undef FOLD

    if (lane < 5) {
        double dn = din[n];
        float4 bb = ((const float4*)b)[lane];    // b row is 16B-aligned (80B stride)
        double o0 = g[0] * dn + (double)bb.x;
        double o1 = g[1] * dn + (double)bb.y;
        double o2 = g[2] * dn + (double)bb.z;
        double o3 = g[3] * dn + (double)bb.w;
        float4 w;
        if (mode == 0) {
            double dd = dout[n];
            w.x = (float)((double)fmaxf((float)o0, 0.0f) * dd);
            w.y = (float)((double)fmaxf((float)o1, 0.0f) * dd);
            w.z = (float)((double)fmaxf((float)o2, 0.0f) * dd);
            w.w = (float)((double)fmaxf((float)o3, 0.0f) * dd);
        } else {
            w.x = (float)o0; w.y = (float)o1; w.z = (float)o2; w.w = (float)o3;
        }
        ((float4*)(hout + (size_t)n * DH))[lane] = w;   // 5 lanes x 16B = 80B row
    }
}

// ---------------- launch ----------------

static inline size_t align256(size_t x) { return (x + 255) & ~(size_t)255; }

extern "C" void kernel_launch(void* const* d_in, const int* in_sizes, int n_in,
                              void* d_out, int out_size, void* d_ws, size_t ws_size,
                              hipStream_t stream) {
    const float* feat    = (const float*)d_in[0];
    const float* W_start = (const float*)d_in[1];
    const float* b_start = (const float*)d_in[2];
    const float* W_mid   = (const float*)d_in[3];
    const float* b_mid   = (const float*)d_in[4];
    const float* W_final = (const float*)d_in[5];
    const float* b_final = (const float*)d_in[6];
    const int*   src     = (const int*)d_in[7];
    const int*   dst     = (const int*)d_in[8];

    const int N = in_sizes[0];              // 100000
    const int E = in_sizes[7];              // 3200000
    const int L = in_sizes[3] / (DH * DH);  // 18 mid layers
    const int K = (N + BKN - 1) / BKN;      // coarse buckets (98)

    // workspace carve-up
    char* p = (char*)d_ws;
    double* dout_d = (double*)p; p += align256(sizeof(double) * N);
    double* din_d  = (double*)p; p += align256(sizeof(double) * N);
    double* x0     = (double*)p; p += align256(sizeof(double) * N);
    int* out_deg   = (int*)p;    p += align256(sizeof(int) * N);
    int* in_deg    = (int*)p;    p += align256(sizeof(int) * N);
    int* row_ptr   = (int*)p;    p += align256(sizeof(int) * (N + 1));
    int* bhist     = (int*)p;    p += align256(sizeof(int) * (MAXK + 1));
    int* bbase     = (int*)p;    p += align256(sizeof(int) * (MAXK + 1));
    int* bcursor   = (int*)p;    p += align256(sizeof(int) * (MAXK + 1));
    int* col       = (int*)p;    p += align256(sizeof(int) * E);
    float* hbuf    = (float*)p;  p += align256(sizeof(float) * N * DH);
    float* ybuf    = (float*)p;  p += align256(sizeof(float) * N * DH);
    // pairs (E ints = 12.8MB) overlays hbuf+ybuf (16MB); dead before layer_start
    int* pairs = (int*)hbuf;

    const int BT = 256;
    int grid_n  = (N + BT - 1) / BT;
    int grid_e  = (E + BT - 1) / BT;
    int grid_c  = (E + CHUNK - 1) / CHUNK;  // 196 chunk blocks
    int grid_nw = (N + 3) / 4;              // 1 wave per node, 4 waves per block

    // ---- graph setup ----
    init_outdeg<<<grid_n, BT, 0, stream>>>(out_deg, N);
    zero_bhist<<<1, MAXK + 1, 0, stream>>>(bhist, K);
    count_outdeg<<<grid_e, BT, 0, stream>>>(src, out_deg, E);
    bucket_hist<<<grid_c, BT, 0, stream>>>(dst, bhist, E, K);
    bucket_scan<<<1, 64, 0, stream>>>(bhist, bbase, bcursor, K);
    bucket_place<<<grid_c, BT, 0, stream>>>(src, dst, bcursor, pairs, E, K);
    node_indeg<<<K, BT, 0, stream>>>(bbase, pairs, in_deg, N);
    compute_norm<<<grid_n, BT, 0, stream>>>(out_deg, in_deg, dout_d, din_d, N);
    build_rowptr<<<1, 1024, 0, stream>>>(in_deg, row_ptr, N, E);
    bucket_fill<<<K, BT, 0, stream>>>(row_ptr, bbase, pairs, col, N);

    // ---- layer 0 (scalar input) ----
    compute_x0<<<grid_n, BT, 0, stream>>>(feat, dout_d, x0, N);
    layer_start<<<grid_nw, BT, 0, stream>>>(x0, row_ptr, col, din_d, dout_d,
                                            W_start, b_start, hbuf, N);

    // ---- 18 mid layers: dense transform + gather-aggregate ----
    for (int l = 0; l < L; ++l) {
        transform<<<grid_n, BT, 0, stream>>>(hbuf, W_mid + (size_t)l * DH * DH, ybuf, N);
        gather_agg<<<grid_nw, BT, 0, stream>>>(ybuf, row_ptr, col, din_d, dout_d,
                                               b_mid + (size_t)l * DH, hbuf, N, 0);
    }

    // ---- final layer: raw store to d_out ----
    transform<<<grid_n, BT, 0, stream>>>(hbuf, W_final, ybuf, N);
    gather_agg<<<grid_nw, BT, 0, stream>>>(ybuf, row_ptr, col, din_d, dout_d,
                                           b_final, (float*)d_out, N, 1);
}

// Round 3
// 1799.569 us; speedup vs baseline: 1.4492x; 1.0835x over previous
//
#include <hip/hip_runtime.h>

#define DH   20        // hidden width
#define BKS  10        // log2 nodes per coarse bucket
#define BKN  1024      // nodes per coarse bucket
#define MAXK 128       // max buckets (N=100000 -> K=98)
#define CHUNK 16384    // edges per bucket_place block

// ---------------- setup kernels ----------------

__global__ void init_outdeg(int* __restrict__ out_deg, int n) {
    int i = blockIdx.x * blockDim.x + threadIdx.x;
    if (i < n) out_deg[i] = 1;              // self-loop contributes 1
}

__global__ void zero_bhist(int* __restrict__ bhist, int K) {
    int i = threadIdx.x;
    if (i <= K) bhist[i] = 0;
}

__global__ void count_outdeg(const int* __restrict__ src, int* __restrict__ out_deg, int E) {
    int e = blockIdx.x * blockDim.x + threadIdx.x;
    if (e < E) atomicAdd(&out_deg[src[e]], 1);
}

__global__ void compute_dout(const int* __restrict__ out_deg, double* __restrict__ dout, int n) {
    int i = blockIdx.x * blockDim.x + threadIdx.x;
    if (i < n) dout[i] = 1.0 / sqrt((double)out_deg[i]);
}

// global per-bucket histogram, LDS-aggregated (196*98 global atomics, not 3.2M)
__global__ __launch_bounds__(256) void bucket_hist(const int* __restrict__ dst,
        int* __restrict__ bhist, int E, int K) {
    __shared__ int h[MAXK];
    for (int i = threadIdx.x; i < K; i += blockDim.x) h[i] = 0;
    __syncthreads();
    int lo = blockIdx.x * CHUNK;
    int hi = lo + CHUNK; if (hi > E) hi = E;
    for (int e = lo + (int)threadIdx.x; e < hi; e += 256)
        atomicAdd(&h[__builtin_nontemporal_load(&dst[e]) >> BKS], 1);
    __syncthreads();
    for (int i = threadIdx.x; i < K; i += blockDim.x)
        if (h[i]) atomicAdd(&bhist[i], h[i]);
}

// exclusive scan of bucket histogram -> contiguous bucket regions + cursors
__global__ void bucket_scan(const int* __restrict__ bhist, int* __restrict__ bbase,
                            int* __restrict__ bcursor, int K) {
    if (threadIdx.x == 0) {
        int run = 0;
        for (int k = 0; k < K; ++k) {
            bbase[k] = run; bcursor[k] = run;
            run += bhist[k];
        }
        bbase[K] = run;
    }
}

// block counting-sort: LDS histogram of a 16K-edge chunk -> one global atomicAdd
// per (block,bucket) reserves a ~670B contiguous run -> near-full-line writes.
__global__ __launch_bounds__(256) void bucket_place(const int* __restrict__ src,
        const int* __restrict__ dst, int* __restrict__ bcursor,
        int* __restrict__ pairs, int E, int K) {
    __shared__ int h[MAXK];
    __shared__ int rbase[MAXK];
    int lo = blockIdx.x * CHUNK;
    int hi = lo + CHUNK; if (hi > E) hi = E;
    for (int i = threadIdx.x; i < K; i += blockDim.x) h[i] = 0;
    __syncthreads();
    for (int e = lo + (int)threadIdx.x; e < hi; e += 256)
        atomicAdd(&h[__builtin_nontemporal_load(&dst[e]) >> BKS], 1);
    __syncthreads();
    for (int i = threadIdx.x; i < K; i += blockDim.x) {
        rbase[i] = h[i] ? atomicAdd(&bcursor[i], h[i]) : 0;
        h[i] = 0;
    }
    __syncthreads();
    for (int e = lo + (int)threadIdx.x; e < hi; e += 256) {
        int d = __builtin_nontemporal_load(&dst[e]);
        int bk = d >> BKS;
        int pos = atomicAdd(&h[bk], 1);
        // src < 2^17, so (src<<10 | dst&1023) fits in 27 bits
        pairs[rbase[bk] + pos] = (__builtin_nontemporal_load(&src[e]) << BKS) | (d & (BKN - 1));
    }
}

// Fused per-bucket build: histogram in-degree from the bucket's pair stream,
// block-scan (seeded by bbase[k] = global exclusive prefix at bucket boundary,
// valid because pairs is bucket-sorted) -> row_ptr + din, then scatter col with
// the scanned values as LDS cursors. Replaces node_indeg + build_rowptr (161us
// single-block serial kernel) + bucket_fill + half of compute_norm.
__global__ __launch_bounds__(256) void bucket_build(
        const int* __restrict__ bbase, const int* __restrict__ pairs,
        int* __restrict__ row_ptr, double* __restrict__ din,
        int* __restrict__ col, int n_nodes, int n_edges) {
    __shared__ int h[BKN];     // in-edge count -> later write cursor
    __shared__ int ts[256];
    int k = blockIdx.x;
    int t = threadIdx.x;
    int nbase = k << BKS;
    int nrem = n_nodes - nbase; if (nrem > BKN) nrem = BKN;
    for (int i = t; i < BKN; i += 256) h[i] = 0;
    __syncthreads();
    int e0 = bbase[k], e1 = bbase[k + 1];
    for (int e = e0 + t; e < e1; e += 256)
        atomicAdd(&h[__builtin_nontemporal_load(&pairs[e]) & (BKN - 1)], 1);
    __syncthreads();
    // block-wide exclusive scan of h[0..BKN), 4 elements per thread
    int i0 = t * 4;
    int c0 = h[i0], c1 = h[i0 + 1], c2 = h[i0 + 2], c3 = h[i0 + 3];
    int s = c0 + c1 + c2 + c3;
    ts[t] = s;
    __syncthreads();
    for (int off = 1; off < 256; off <<= 1) {
        int v = (t >= off) ? ts[t - off] : 0;
        __syncthreads();
        ts[t] += v;
        __syncthreads();
    }
    int run = bbase[k] + ts[t] - s;          // global exclusive prefix
    int cs[4] = {c0, c1, c2, c3};
#pragma unroll
    for (int j = 0; j < 4; ++j) {
        int idx = i0 + j;
        if (idx < nrem) {
            row_ptr[nbase + idx] = run;
            din[nbase + idx] = 1.0 / sqrt((double)(cs[j] + 1));   // +1 self loop
        }
        h[idx] = run;                        // cursor for scatter phase
        run += cs[j];
    }
    if (t == 0 && nbase + BKN >= n_nodes) row_ptr[n_nodes] = n_edges;
    __syncthreads();
    // scatter this bucket's stream into CSR (col writes confined to L2-hot window)
    for (int e = e0 + t; e < e1; e += 256) {
        int pk = __builtin_nontemporal_load(&pairs[e]);
        int slot = atomicAdd(&h[pk & (BKN - 1)], 1);   // LDS atomic, cheap
        col[slot] = pk >> BKS;
    }
}

// ---------------- layer kernels ----------------

// x0[n] = feat[n] * dout[n]   (layer 0 input is N x 1)
__global__ void compute_x0(const float* __restrict__ feat, const double* __restrict__ dout,
                           double* __restrict__ x0, int n) {
    int i = blockIdx.x * blockDim.x + threadIdx.x;
    if (i < n) x0[i] = (double)feat[i] * dout[i];
}

// layer 0: g[n] = x0[n] + sum_{s in N(n)} x0[s]  (scalar gather, 64 lanes edge-parallel)
__global__ __launch_bounds__(256) void layer_start(
        const double* __restrict__ x0, const int* __restrict__ row_ptr,
        const int* __restrict__ col, const double* __restrict__ din,
        const double* __restrict__ dout, const float* __restrict__ W,
        const float* __restrict__ b, float* __restrict__ xout, int n_nodes) {
    int n    = (blockIdx.x * blockDim.x + threadIdx.x) >> 6;   // one wave per node
    int lane = threadIdx.x & 63;
    if (n >= n_nodes) return;
    double a = (lane == 0) ? x0[n] : 0.0;   // self loop
    int e0 = row_ptr[n], e1 = row_ptr[n + 1];
    for (int e = e0 + lane; e < e1; e += 64)
        a += x0[__builtin_nontemporal_load(&col[e])];
#pragma unroll
    for (int off = 32; off > 0; off >>= 1)
        a += __shfl_xor(a, off, 64);
    if (lane < DH) {
        double v = a * din[n] * (double)W[lane] + (double)b[lane];
        float r = fmaxf((float)v, 0.0f);
        xout[(long)n * DH + lane] = (float)((double)r * dout[n]);
    }
}

// dense transform: y[n] = h'[n] @ W   (h' already carries the dout scaling).
__global__ __launch_bounds__(256) void transform(
        const float* __restrict__ h, const float* __restrict__ W,
        float* __restrict__ y, int n_nodes) {
    __shared__ float Wl[DH * DH];
    for (int i = threadIdx.x; i < DH * DH; i += blockDim.x) Wl[i] = W[i];
    __syncthreads();
    int n = blockIdx.x * blockDim.x + threadIdx.x;
    if (n >= n_nodes) return;
    const float4* h4 = (const float4*)(h + (size_t)n * DH);
    float4 a0 = h4[0], a1 = h4[1], a2 = h4[2], a3 = h4[3], a4 = h4[4];
    float hv[DH] = {a0.x, a0.y, a0.z, a0.w, a1.x, a1.y, a1.z, a1.w,
                    a2.x, a2.y, a2.z, a2.w, a3.x, a3.y, a3.z, a3.w,
                    a4.x, a4.y, a4.z, a4.w};
    double acc[DH];
#pragma unroll
    for (int j = 0; j < DH; ++j) acc[j] = 0.0;
#pragma unroll
    for (int k = 0; k < DH; ++k) {
        double hk = (double)hv[k];
#pragma unroll
        for (int j = 0; j < DH; ++j)
            acc[j] += hk * (double)Wl[k * DH + j];   // LDS broadcast, conflict-free
    }
    float4* y4 = (float4*)(y + (size_t)n * DH);
    y4[0] = make_float4((float)acc[0],  (float)acc[1],  (float)acc[2],  (float)acc[3]);
    y4[1] = make_float4((float)acc[4],  (float)acc[5],  (float)acc[6],  (float)acc[7]);
    y4[2] = make_float4((float)acc[8],  (float)acc[9],  (float)acc[10], (float)acc[11]);
    y4[3] = make_float4((float)acc[12], (float)acc[13], (float)acc[14], (float)acc[15]);
    y4[4] = make_float4((float)acc[16], (float)acc[17], (float)acc[18], (float)acc[19]);
}

// gather+aggregate: h'[n] = relu(din[n]*(y[n] + sum_{s in N(n)} y[s]) + b) * dout[n]
__global__ __launch_bounds__(256, 8) void gather_agg(
        const float* __restrict__ y, const int* __restrict__ row_ptr,
        const int* __restrict__ col, const double* __restrict__ din,
        const double* __restrict__ dout, const float* __restrict__ b,
        float* __restrict__ hout, int n_nodes, int mode) {
    int n    = (blockIdx.x * blockDim.x + threadIdx.x) >> 6;   // one wave per node
    int lane = threadIdx.x & 63;
    if (n >= n_nodes) return;

    int ep = lane / 5;           // edge slot 0..12 (lanes 60..63 -> ep=12, inactive)
    int jq = lane - ep * 5;      // float4 quarter 0..4
    const float4* __restrict__ y4 = (const float4*)y;

    int e0 = row_ptr[n], e1 = row_ptr[n + 1];

    int s0 = -1, s1 = -1, s2 = -1, s3 = -1;
    if (ep < 12) {
        int p = e0 + ep;
        if (p      < e1) s0 = __builtin_nontemporal_load(&col[p]);
        if (p + 12 < e1) s1 = __builtin_nontemporal_load(&col[p + 12]);
        if (p + 24 < e1) s2 = __builtin_nontemporal_load(&col[p + 24]);
        if (p + 36 < e1) s3 = __builtin_nontemporal_load(&col[p + 36]);
    }
    bool p0 = s0 >= 0, p1 = s1 >= 0, p2 = s2 >= 0, p3 = s3 >= 0;
    float4 v0 = y4[(p0 ? s0 : n) * 5 + jq];
    float4 v1 = y4[(p1 ? s1 : n) * 5 + jq];
    float4 v2 = y4[(p2 ? s2 : n) * 5 + jq];
    float4 v3 = y4[(p3 ? s3 : n) * 5 + jq];

    double g[4] = {0.0, 0.0, 0.0, 0.0};
    if (ep == 0) {               // self loop handled by slot 0
        float4 v = y4[n * 5 + jq];
        g[0] = (double)v.x; g[1] = (double)v.y; g[2] = (double)v.z; g[3] = (double)v.w;
    }
    if (p0) { g[0] += (double)v0.x; g[1] += (double)v0.y; g[2] += (double)v0.z; g[3] += (double)v0.w; }
    if (p1) { g[0] += (double)v1.x; g[1] += (double)v1.y; g[2] += (double)v1.z; g[3] += (double)v1.w; }
    if (p2) { g[0] += (double)v2.x; g[1] += (double)v2.y; g[2] += (double)v2.z; g[3] += (double)v2.w; }
    if (p3) { g[0] += (double)v3.x; g[1] += (double)v3.y; g[2] += (double)v3.z; g[3] += (double)v3.w; }

    // rare tail: deg > 48 (wave-uniform branch)
    if (e1 - e0 > 48) {
        if (ep < 12) {
            for (int e = e0 + 48 + ep; e < e1; e += 12) {
                int s = __builtin_nontemporal_load(&col[e]);
                float4 v = y4[s * 5 + jq];
                g[0] += (double)v.x; g[1] += (double)v.y;
                g[2] += (double)v.z; g[3] += (double)v.w;
            }
        }
    }

    // fold 12 edge slots down to slot 0
#define FOLD(LIM, DELTA)                                                        \
    {                                                                           \
        int srcl = lane + DELTA; if (srcl > 63) srcl = lane;                    \
        double t0 = __shfl(g[0], srcl, 64);                                     \
        double t1 = __shfl(g[1], srcl, 64);                                     \
        double t2 = __shfl(g[2], srcl, 64);                                     \
        double t3 = __shfl(g[3], srcl, 64);                                     \
        if (ep < (LIM)) { g[0] += t0; g[1] += t1; g[2] += t2; g[3] += t3; }     \
    }
    FOLD(4, 40)   // ep(0..3)  += ep+8
    FOLD(4, 20)   // ep(0..3)  += ep+4
    FOLD(2, 10)   // ep(0..1)  += ep+2
    FOLD(1, 5)    // ep(0)     += ep+1
#undef FOLD

    if (lane < 5) {
        double dn = din[n];
        float4 bb = ((const float4*)b)[lane];    // b row is 16B-aligned (80B stride)
        double o0 = g[0] * dn + (double)bb.x;
        double o1 = g[1] * dn + (double)bb.y;
        double o2 = g[2] * dn + (double)bb.z;
        double o3 = g[3] * dn + (double)bb.w;
        float4 w;
        if (mode == 0) {
            double dd = dout[n];
            w.x = (float)((double)fmaxf((float)o0, 0.0f) * dd);
            w.y = (float)((double)fmaxf((float)o1, 0.0f) * dd);
            w.z = (float)((double)fmaxf((float)o2, 0.0f) * dd);
            w.w = (float)((double)fmaxf((float)o3, 0.0f) * dd);
        } else {
            w.x = (float)o0; w.y = (float)o1; w.z = (float)o2; w.w = (float)o3;
        }
        ((float4*)(hout + (size_t)n * DH))[lane] = w;   // 5 lanes x 16B = 80B row
    }
}

// ---------------- launch ----------------

static inline size_t align256(size_t x) { return (x + 255) & ~(size_t)255; }

extern "C" void kernel_launch(void* const* d_in, const int* in_sizes, int n_in,
                              void* d_out, int out_size, void* d_ws, size_t ws_size,
                              hipStream_t stream) {
    const float* feat    = (const float*)d_in[0];
    const float* W_start = (const float*)d_in[1];
    const float* b_start = (const float*)d_in[2];
    const float* W_mid   = (const float*)d_in[3];
    const float* b_mid   = (const float*)d_in[4];
    const float* W_final = (const float*)d_in[5];
    const float* b_final = (const float*)d_in[6];
    const int*   src     = (const int*)d_in[7];
    const int*   dst     = (const int*)d_in[8];

    const int N = in_sizes[0];              // 100000
    const int E = in_sizes[7];              // 3200000
    const int L = in_sizes[3] / (DH * DH);  // 18 mid layers
    const int K = (N + BKN - 1) / BKN;      // coarse buckets (98)

    // workspace carve-up
    char* p = (char*)d_ws;
    double* dout_d = (double*)p; p += align256(sizeof(double) * N);
    double* din_d  = (double*)p; p += align256(sizeof(double) * N);
    double* x0     = (double*)p; p += align256(sizeof(double) * N);
    int* out_deg   = (int*)p;    p += align256(sizeof(int) * N);
    int* row_ptr   = (int*)p;    p += align256(sizeof(int) * (N + 1));
    int* bhist     = (int*)p;    p += align256(sizeof(int) * (MAXK + 1));
    int* bbase     = (int*)p;    p += align256(sizeof(int) * (MAXK + 1));
    int* bcursor   = (int*)p;    p += align256(sizeof(int) * (MAXK + 1));
    int* col       = (int*)p;    p += align256(sizeof(int) * E);
    float* hbuf    = (float*)p;  p += align256(sizeof(float) * N * DH);
    float* ybuf    = (float*)p;  p += align256(sizeof(float) * N * DH);
    // pairs (E ints = 12.8MB) overlays hbuf+ybuf (16MB); dead before layer_start
    int* pairs = (int*)hbuf;

    const int BT = 256;
    int grid_n  = (N + BT - 1) / BT;
    int grid_e  = (E + BT - 1) / BT;
    int grid_c  = (E + CHUNK - 1) / CHUNK;  // 196 chunk blocks
    int grid_nw = (N + 3) / 4;              // 1 wave per node, 4 waves per block

    // ---- graph setup ----
    init_outdeg<<<grid_n, BT, 0, stream>>>(out_deg, N);
    zero_bhist<<<1, 128, 0, stream>>>(bhist, K);
    count_outdeg<<<grid_e, BT, 0, stream>>>(src, out_deg, E);
    bucket_hist<<<grid_c, BT, 0, stream>>>(dst, bhist, E, K);
    bucket_scan<<<1, 64, 0, stream>>>(bhist, bbase, bcursor, K);
    bucket_place<<<grid_c, BT, 0, stream>>>(src, dst, bcursor, pairs, E, K);
    bucket_build<<<K, BT, 0, stream>>>(bbase, pairs, row_ptr, din_d, col, N, E);
    compute_dout<<<grid_n, BT, 0, stream>>>(out_deg, dout_d, N);

    // ---- layer 0 (scalar input) ----
    compute_x0<<<grid_n, BT, 0, stream>>>(feat, dout_d, x0, N);
    layer_start<<<grid_nw, BT, 0, stream>>>(x0, row_ptr, col, din_d, dout_d,
                                            W_start, b_start, hbuf, N);

    // ---- 18 mid layers: dense transform + gather-aggregate ----
    for (int l = 0; l < L; ++l) {
        transform<<<grid_n, BT, 0, stream>>>(hbuf, W_mid + (size_t)l * DH * DH, ybuf, N);
        gather_agg<<<grid_nw, BT, 0, stream>>>(ybuf, row_ptr, col, din_d, dout_d,
                                               b_mid + (size_t)l * DH, hbuf, N, 0);
    }

    // ---- final layer: raw store to d_out ----
    transform<<<grid_n, BT, 0, stream>>>(hbuf, W_final, ybuf, N);
    gather_agg<<<grid_nw, BT, 0, stream>>>(ybuf, row_ptr, col, din_d, dout_d,
                                           b_final, (float*)d_out, N, 1);
}

// Round 4
// 1704.430 us; speedup vs baseline: 1.5301x; 1.0558x over previous
//
#include <hip/hip_runtime.h>

#define DH   20        // hidden width
#define BKS  10        // log2 nodes per coarse bucket
#define BKN  1024      // nodes per coarse bucket
#define MAXK 128       // max buckets (N=100000 -> K=98)
#define CHUNK 8192     // edges per hist/place block (391 blocks > 256 CUs)

// ---------------- setup kernels ----------------

__global__ void zero_bhist2(int* __restrict__ bhist_d, int* __restrict__ bhist_s) {
    int i = threadIdx.x;
    if (i < MAXK) { bhist_d[i] = 0; bhist_s[i] = 0; }
}

// one read pass over src+dst, two LDS histograms (dst-buckets and src-buckets)
__global__ __launch_bounds__(256) void bucket_hist2(const int* __restrict__ src,
        const int* __restrict__ dst, int* __restrict__ bhist_d,
        int* __restrict__ bhist_s, int E, int K) {
    __shared__ int hd[MAXK];
    __shared__ int hs[MAXK];
    for (int i = threadIdx.x; i < K; i += blockDim.x) { hd[i] = 0; hs[i] = 0; }
    __syncthreads();
    int lo = blockIdx.x * CHUNK;
    int hi = lo + CHUNK; if (hi > E) hi = E;
    for (int e = lo + (int)threadIdx.x; e < hi; e += 256) {
        atomicAdd(&hd[__builtin_nontemporal_load(&dst[e]) >> BKS], 1);
        atomicAdd(&hs[__builtin_nontemporal_load(&src[e]) >> BKS], 1);
    }
    __syncthreads();
    for (int i = threadIdx.x; i < K; i += blockDim.x) {
        if (hd[i]) atomicAdd(&bhist_d[i], hd[i]);
        if (hs[i]) atomicAdd(&bhist_s[i], hs[i]);
    }
}

// exclusive scan of both bucket histograms -> contiguous regions + cursors
__global__ void bucket_scan2(const int* __restrict__ bhist_d, int* __restrict__ bbase_d,
                             int* __restrict__ bcursor_d, const int* __restrict__ bhist_s,
                             int* __restrict__ bbase_s, int* __restrict__ bcursor_s, int K) {
    if (threadIdx.x == 0) {
        int run = 0;
        for (int k = 0; k < K; ++k) {
            bbase_d[k] = run; bcursor_d[k] = run;
            run += bhist_d[k];
        }
        bbase_d[K] = run;
    } else if (threadIdx.x == 1) {
        int run = 0;
        for (int k = 0; k < K; ++k) {
            bbase_s[k] = run; bcursor_s[k] = run;
            run += bhist_s[k];
        }
        bbase_s[K] = run;
    }
}

// block counting-sort, both axes in one pass: LDS histograms -> one global
// atomicAdd per (block,bucket) reserves a contiguous run -> near-full-line
// writes. pairs = (src<<10|dst&1023) sorted by dst-bucket; ssort = (src&1023)
// sorted by src-bucket (feeds out-degree histogram).
__global__ __launch_bounds__(256) void bucket_place2(const int* __restrict__ src,
        const int* __restrict__ dst, int* __restrict__ bcursor_d,
        int* __restrict__ bcursor_s, int* __restrict__ pairs,
        int* __restrict__ ssort, int E, int K) {
    __shared__ int hd[MAXK];
    __shared__ int hs[MAXK];
    __shared__ int rbd[MAXK];
    __shared__ int rbs[MAXK];
    int lo = blockIdx.x * CHUNK;
    int hi = lo + CHUNK; if (hi > E) hi = E;
    for (int i = threadIdx.x; i < K; i += blockDim.x) { hd[i] = 0; hs[i] = 0; }
    __syncthreads();
    for (int e = lo + (int)threadIdx.x; e < hi; e += 256) {
        atomicAdd(&hd[__builtin_nontemporal_load(&dst[e]) >> BKS], 1);
        atomicAdd(&hs[__builtin_nontemporal_load(&src[e]) >> BKS], 1);
    }
    __syncthreads();
    for (int i = threadIdx.x; i < K; i += blockDim.x) {
        rbd[i] = hd[i] ? atomicAdd(&bcursor_d[i], hd[i]) : 0;
        rbs[i] = hs[i] ? atomicAdd(&bcursor_s[i], hs[i]) : 0;
        hd[i] = 0; hs[i] = 0;
    }
    __syncthreads();
    for (int e = lo + (int)threadIdx.x; e < hi; e += 256) {
        int d = __builtin_nontemporal_load(&dst[e]);
        int s = __builtin_nontemporal_load(&src[e]);
        int bkd = d >> BKS;
        int pd = atomicAdd(&hd[bkd], 1);
        pairs[rbd[bkd] + pd] = (s << BKS) | (d & (BKN - 1));
        int bks = s >> BKS;
        int ps = atomicAdd(&hs[bks], 1);
        ssort[rbs[bks] + ps] = s & (BKN - 1);
    }
}

// per-src-bucket LDS histogram over its ssort segment -> dout = 1/sqrt(outdeg)
__global__ __launch_bounds__(256) void bucket_outdeg(const int* __restrict__ bbase_s,
        const int* __restrict__ ssort, double* __restrict__ dout, int n_nodes) {
    __shared__ int h[BKN];
    int k = blockIdx.x;
    int nbase = k << BKS;
    int nrem = n_nodes - nbase; if (nrem > BKN) nrem = BKN;
    for (int i = threadIdx.x; i < BKN; i += 256) h[i] = 1;   // self loop
    __syncthreads();
    int e0 = bbase_s[k], e1 = bbase_s[k + 1];
    for (int e = e0 + (int)threadIdx.x; e < e1; e += 256)
        atomicAdd(&h[__builtin_nontemporal_load(&ssort[e])], 1);
    __syncthreads();
    for (int i = threadIdx.x; i < nrem; i += 256)
        dout[nbase + i] = 1.0 / sqrt((double)h[i]);
}

// Fused per-bucket build: histogram in-degree from the bucket's pair stream,
// block-scan (seeded by bbase[k] = global exclusive prefix at bucket boundary,
// valid because pairs is bucket-sorted) -> row_ptr + din, then scatter col with
// the scanned values as LDS cursors.
__global__ __launch_bounds__(256) void bucket_build(
        const int* __restrict__ bbase, const int* __restrict__ pairs,
        int* __restrict__ row_ptr, double* __restrict__ din,
        int* __restrict__ col, int n_nodes, int n_edges) {
    __shared__ int h[BKN];     // in-edge count -> later write cursor
    __shared__ int ts[256];
    int k = blockIdx.x;
    int t = threadIdx.x;
    int nbase = k << BKS;
    int nrem = n_nodes - nbase; if (nrem > BKN) nrem = BKN;
    for (int i = t; i < BKN; i += 256) h[i] = 0;
    __syncthreads();
    int e0 = bbase[k], e1 = bbase[k + 1];
    for (int e = e0 + t; e < e1; e += 256)
        atomicAdd(&h[__builtin_nontemporal_load(&pairs[e]) & (BKN - 1)], 1);
    __syncthreads();
    // block-wide exclusive scan of h[0..BKN), 4 elements per thread
    int i0 = t * 4;
    int c0 = h[i0], c1 = h[i0 + 1], c2 = h[i0 + 2], c3 = h[i0 + 3];
    int s = c0 + c1 + c2 + c3;
    ts[t] = s;
    __syncthreads();
    for (int off = 1; off < 256; off <<= 1) {
        int v = (t >= off) ? ts[t - off] : 0;
        __syncthreads();
        ts[t] += v;
        __syncthreads();
    }
    int run = bbase[k] + ts[t] - s;          // global exclusive prefix
    int cs[4] = {c0, c1, c2, c3};
#pragma unroll
    for (int j = 0; j < 4; ++j) {
        int idx = i0 + j;
        if (idx < nrem) {
            row_ptr[nbase + idx] = run;
            din[nbase + idx] = 1.0 / sqrt((double)(cs[j] + 1));   // +1 self loop
        }
        h[idx] = run;                        // cursor for scatter phase
        run += cs[j];
    }
    if (t == 0 && nbase + BKN >= n_nodes) row_ptr[n_nodes] = n_edges;
    __syncthreads();
    // scatter this bucket's stream into CSR (col writes confined to L2-hot window)
    for (int e = e0 + t; e < e1; e += 256) {
        int pk = __builtin_nontemporal_load(&pairs[e]);
        int slot = atomicAdd(&h[pk & (BKN - 1)], 1);   // LDS atomic, cheap
        col[slot] = pk >> BKS;
    }
}

// ---------------- layer kernels ----------------

// x0[n] = feat[n] * dout[n]   (layer 0 input is N x 1)
__global__ void compute_x0(const float* __restrict__ feat, const double* __restrict__ dout,
                           double* __restrict__ x0, int n) {
    int i = blockIdx.x * blockDim.x + threadIdx.x;
    if (i < n) x0[i] = (double)feat[i] * dout[i];
}

// layer 0: g[n] = x0[n] + sum_{s in N(n)} x0[s]  (scalar gather, 64 lanes edge-parallel)
__global__ __launch_bounds__(256) void layer_start(
        const double* __restrict__ x0, const int* __restrict__ row_ptr,
        const int* __restrict__ col, const double* __restrict__ din,
        const double* __restrict__ dout, const float* __restrict__ W,
        const float* __restrict__ b, float* __restrict__ xout, int n_nodes) {
    int n    = (blockIdx.x * blockDim.x + threadIdx.x) >> 6;   // one wave per node
    int lane = threadIdx.x & 63;
    if (n >= n_nodes) return;
    double a = (lane == 0) ? x0[n] : 0.0;   // self loop
    int e0 = row_ptr[n], e1 = row_ptr[n + 1];
    for (int e = e0 + lane; e < e1; e += 64)
        a += x0[__builtin_nontemporal_load(&col[e])];
#pragma unroll
    for (int off = 32; off > 0; off >>= 1)
        a += __shfl_xor(a, off, 64);
    if (lane < DH) {
        double v = a * din[n] * (double)W[lane] + (double)b[lane];
        float r = fmaxf((float)v, 0.0f);
        xout[(long)n * DH + lane] = (float)((double)r * dout[n]);
    }
}

// dense transform: y[n] = h'[n] @ W   (h' already carries the dout scaling).
__global__ __launch_bounds__(256) void transform(
        const float* __restrict__ h, const float* __restrict__ W,
        float* __restrict__ y, int n_nodes) {
    __shared__ float Wl[DH * DH];
    for (int i = threadIdx.x; i < DH * DH; i += blockDim.x) Wl[i] = W[i];
    __syncthreads();
    int n = blockIdx.x * blockDim.x + threadIdx.x;
    if (n >= n_nodes) return;
    const float4* h4 = (const float4*)(h + (size_t)n * DH);
    float4 a0 = h4[0], a1 = h4[1], a2 = h4[2], a3 = h4[3], a4 = h4[4];
    float hv[DH] = {a0.x, a0.y, a0.z, a0.w, a1.x, a1.y, a1.z, a1.w,
                    a2.x, a2.y, a2.z, a2.w, a3.x, a3.y, a3.z, a3.w,
                    a4.x, a4.y, a4.z, a4.w};
    double acc[DH];
#pragma unroll
    for (int j = 0; j < DH; ++j) acc[j] = 0.0;
#pragma unroll
    for (int k = 0; k < DH; ++k) {
        double hk = (double)hv[k];
#pragma unroll
        for (int j = 0; j < DH; ++j)
            acc[j] += hk * (double)Wl[k * DH + j];   // LDS broadcast, conflict-free
    }
    float4* y4 = (float4*)(y + (size_t)n * DH);
    y4[0] = make_float4((float)acc[0],  (float)acc[1],  (float)acc[2],  (float)acc[3]);
    y4[1] = make_float4((float)acc[4],  (float)acc[5],  (float)acc[6],  (float)acc[7]);
    y4[2] = make_float4((float)acc[8],  (float)acc[9],  (float)acc[10], (float)acc[11]);
    y4[3] = make_float4((float)acc[12], (float)acc[13], (float)acc[14], (float)acc[15]);
    y4[4] = make_float4((float)acc[16], (float)acc[17], (float)acc[18], (float)acc[19]);
}

// gather+aggregate: h'[n] = relu(din[n]*(y[n] + sum_{s in N(n)} y[s]) + b) * dout[n]
__global__ __launch_bounds__(256, 8) void gather_agg(
        const float* __restrict__ y, const int* __restrict__ row_ptr,
        const int* __restrict__ col, const double* __restrict__ din,
        const double* __restrict__ dout, const float* __restrict__ b,
        float* __restrict__ hout, int n_nodes, int mode) {
    int n    = (blockIdx.x * blockDim.x + threadIdx.x) >> 6;   // one wave per node
    int lane = threadIdx.x & 63;
    if (n >= n_nodes) return;

    int ep = lane / 5;           // edge slot 0..12 (lanes 60..63 -> ep=12, inactive)
    int jq = lane - ep * 5;      // float4 quarter 0..4
    const float4* __restrict__ y4 = (const float4*)y;

    int e0 = row_ptr[n], e1 = row_ptr[n + 1];

    int s0 = -1, s1 = -1, s2 = -1, s3 = -1;
    if (ep < 12) {
        int p = e0 + ep;
        if (p      < e1) s0 = __builtin_nontemporal_load(&col[p]);
        if (p + 12 < e1) s1 = __builtin_nontemporal_load(&col[p + 12]);
        if (p + 24 < e1) s2 = __builtin_nontemporal_load(&col[p + 24]);
        if (p + 36 < e1) s3 = __builtin_nontemporal_load(&col[p + 36]);
    }
    bool p0 = s0 >= 0, p1 = s1 >= 0, p2 = s2 >= 0, p3 = s3 >= 0;
    float4 v0 = y4[(p0 ? s0 : n) * 5 + jq];
    float4 v1 = y4[(p1 ? s1 : n) * 5 + jq];
    float4 v2 = y4[(p2 ? s2 : n) * 5 + jq];
    float4 v3 = y4[(p3 ? s3 : n) * 5 + jq];

    double g[4] = {0.0, 0.0, 0.0, 0.0};
    if (ep == 0) {               // self loop handled by slot 0
        float4 v = y4[n * 5 + jq];
        g[0] = (double)v.x; g[1] = (double)v.y; g[2] = (double)v.z; g[3] = (double)v.w;
    }
    if (p0) { g[0] += (double)v0.x; g[1] += (double)v0.y; g[2] += (double)v0.z; g[3] += (double)v0.w; }
    if (p1) { g[0] += (double)v1.x; g[1] += (double)v1.y; g[2] += (double)v1.z; g[3] += (double)v1.w; }
    if (p2) { g[0] += (double)v2.x; g[1] += (double)v2.y; g[2] += (double)v2.z; g[3] += (double)v2.w; }
    if (p3) { g[0] += (double)v3.x; g[1] += (double)v3.y; g[2] += (double)v3.z; g[3] += (double)v3.w; }

    // rare tail: deg > 48 (wave-uniform branch)
    if (e1 - e0 > 48) {
        if (ep < 12) {
            for (int e = e0 + 48 + ep; e < e1; e += 12) {
                int s = __builtin_nontemporal_load(&col[e]);
                float4 v = y4[s * 5 + jq];
                g[0] += (double)v.x; g[1] += (double)v.y;
                g[2] += (double)v.z; g[3] += (double)v.w;
            }
        }
    }

    // fold 12 edge slots down to slot 0
#define FOLD(LIM, DELTA)                                                        \
    {                                                                           \
        int srcl = lane + DELTA; if (srcl > 63) srcl = lane;                    \
        double t0 = __shfl(g[0], srcl, 64);                                     \
        double t1 = __shfl(g[1], srcl, 64);                                     \
        double t2 = __shfl(g[2], srcl, 64);                                     \
        double t3 = __shfl(g[3], srcl, 64);                                     \
        if (ep < (LIM)) { g[0] += t0; g[1] += t1; g[2] += t2; g[3] += t3; }     \
    }
    FOLD(4, 40)   // ep(0..3)  += ep+8
    FOLD(4, 20)   // ep(0..3)  += ep+4
    FOLD(2, 10)   // ep(0..1)  += ep+2
    FOLD(1, 5)    // ep(0)     += ep+1
#undef FOLD

    if (lane < 5) {
        double dn = din[n];
        float4 bb = ((const float4*)b)[lane];    // b row is 16B-aligned (80B stride)
        double o0 = g[0] * dn + (double)bb.x;
        double o1 = g[1] * dn + (double)bb.y;
        double o2 = g[2] * dn + (double)bb.z;
        double o3 = g[3] * dn + (double)bb.w;
        float4 w;
        if (mode == 0) {
            double dd = dout[n];
            w.x = (float)((double)fmaxf((float)o0, 0.0f) * dd);
            w.y = (float)((double)fmaxf((float)o1, 0.0f) * dd);
            w.z = (float)((double)fmaxf((float)o2, 0.0f) * dd);
            w.w = (float)((double)fmaxf((float)o3, 0.0f) * dd);
        } else {
            w.x = (float)o0; w.y = (float)o1; w.z = (float)o2; w.w = (float)o3;
        }
        ((float4*)(hout + (size_t)n * DH))[lane] = w;   // 5 lanes x 16B = 80B row
    }
}

// ---------------- launch ----------------

static inline size_t align256(size_t x) { return (x + 255) & ~(size_t)255; }

extern "C" void kernel_launch(void* const* d_in, const int* in_sizes, int n_in,
                              void* d_out, int out_size, void* d_ws, size_t ws_size,
                              hipStream_t stream) {
    const float* feat    = (const float*)d_in[0];
    const float* W_start = (const float*)d_in[1];
    const float* b_start = (const float*)d_in[2];
    const float* W_mid   = (const float*)d_in[3];
    const float* b_mid   = (const float*)d_in[4];
    const float* W_final = (const float*)d_in[5];
    const float* b_final = (const float*)d_in[6];
    const int*   src     = (const int*)d_in[7];
    const int*   dst     = (const int*)d_in[8];

    const int N = in_sizes[0];              // 100000
    const int E = in_sizes[7];              // 3200000
    const int L = in_sizes[3] / (DH * DH);  // 18 mid layers
    const int K = (N + BKN - 1) / BKN;      // coarse buckets (98)

    // workspace carve-up
    char* p = (char*)d_ws;
    double* dout_d = (double*)p; p += align256(sizeof(double) * N);
    double* din_d  = (double*)p; p += align256(sizeof(double) * N);
    double* x0     = (double*)p; p += align256(sizeof(double) * N);
    int* row_ptr   = (int*)p;    p += align256(sizeof(int) * (N + 1));
    int* bhist_d   = (int*)p;    p += align256(sizeof(int) * (MAXK + 1));
    int* bbase_d   = (int*)p;    p += align256(sizeof(int) * (MAXK + 1));
    int* bcursor_d = (int*)p;    p += align256(sizeof(int) * (MAXK + 1));
    int* bhist_s   = (int*)p;    p += align256(sizeof(int) * (MAXK + 1));
    int* bbase_s   = (int*)p;    p += align256(sizeof(int) * (MAXK + 1));
    int* bcursor_s = (int*)p;    p += align256(sizeof(int) * (MAXK + 1));
    int* col       = (int*)p;    p += align256(sizeof(int) * E);
    float* hbuf    = (float*)p;  p += align256(sizeof(float) * N * DH);
    float* ybuf    = (float*)p;  p += align256(sizeof(float) * N * DH);
    // pairs (E ints = 12.8MB) overlays hbuf+ybuf (16MB); dead before layer_start
    int* pairs = (int*)hbuf;
    // ssort (E ints) aliases col: consumed by bucket_outdeg BEFORE bucket_build
    // overwrites the region with the real CSR
    int* ssort = col;

    const int BT = 256;
    int grid_n  = (N + BT - 1) / BT;
    int grid_c  = (E + CHUNK - 1) / CHUNK;  // 391 chunk blocks
    int grid_nw = (N + 3) / 4;              // 1 wave per node, 4 waves per block

    // ---- graph setup ----
    zero_bhist2<<<1, MAXK, 0, stream>>>(bhist_d, bhist_s);
    bucket_hist2<<<grid_c, BT, 0, stream>>>(src, dst, bhist_d, bhist_s, E, K);
    bucket_scan2<<<1, 64, 0, stream>>>(bhist_d, bbase_d, bcursor_d,
                                       bhist_s, bbase_s, bcursor_s, K);
    bucket_place2<<<grid_c, BT, 0, stream>>>(src, dst, bcursor_d, bcursor_s,
                                             pairs, ssort, E, K);
    bucket_outdeg<<<K, BT, 0, stream>>>(bbase_s, ssort, dout_d, N);
    bucket_build<<<K, BT, 0, stream>>>(bbase_d, pairs, row_ptr, din_d, col, N, E);

    // ---- layer 0 (scalar input) ----
    compute_x0<<<grid_n, BT, 0, stream>>>(feat, dout_d, x0, N);
    layer_start<<<grid_nw, BT, 0, stream>>>(x0, row_ptr, col, din_d, dout_d,
                                            W_start, b_start, hbuf, N);

    // ---- 18 mid layers: dense transform + gather-aggregate ----
    for (int l = 0; l < L; ++l) {
        transform<<<grid_n, BT, 0, stream>>>(hbuf, W_mid + (size_t)l * DH * DH, ybuf, N);
        gather_agg<<<grid_nw, BT, 0, stream>>>(ybuf, row_ptr, col, din_d, dout_d,
                                               b_mid + (size_t)l * DH, hbuf, N, 0);
    }

    // ---- final layer: raw store to d_out ----
    transform<<<grid_n, BT, 0, stream>>>(hbuf, W_final, ybuf, N);
    gather_agg<<<grid_nw, BT, 0, stream>>>(ybuf, row_ptr, col, din_d, dout_d,
                                           b_final, (float*)d_out, N, 1);
}